// Round 1
// baseline (420.973 us; speedup 1.0000x reference)
//
#include <hip/hip_runtime.h>
#include <math.h>

// Problem constants (from reference)
#define GRID_HW   13
#define NBOX      5
#define NCLASS    80
#define REC       85                       // 5 + NCLASS floats per cell
#define CPB_CELLS (GRID_HW*GRID_HW*NBOX)   // 845 cells per batch element
#define T_BOXES   50
#define CPB       64                       // cells per block
#define THREADS   256

__device__ __constant__ float c_anchors[10] = {
    0.57273f, 0.677385f, 1.87446f, 2.06253f, 3.33843f,
    5.47434f, 7.88282f, 3.52778f, 9.77052f, 9.16828f};

// acc layout: [0]=sum_xy [1]=sum_wh [2]=sum_conf [3]=sum_ce
//             [4]=nb_coord [5]=nb_conf [6]=nb_class
__global__ __launch_bounds__(THREADS)
void yolo_loss_main(const float* __restrict__ y_true,
                    const float* __restrict__ y_pred,
                    const float* __restrict__ tboxes,
                    double* __restrict__ acc,
                    int n_cells)
{
    __shared__ float lds_yt[CPB * REC];   // 21760 B
    __shared__ float lds_yp[CPB * REC];   // 21760 B
    __shared__ double red[4][7];

    const int tid   = threadIdx.x;
    const int cell0 = blockIdx.x * CPB;

    // ---- coalesced global -> LDS staging (float4) ----
    {
        const size_t base = (size_t)cell0 * REC;
        long long avail_ll = (long long)n_cells * REC - (long long)base;
        int navail = (avail_ll > (long long)(CPB * REC)) ? (CPB * REC)
                    : (avail_ll < 0 ? 0 : (int)avail_ll);
        int n4 = navail >> 2;
        const float4* gt = (const float4*)(y_true + base);
        const float4* gp = (const float4*)(y_pred + base);
        float4* st = (float4*)lds_yt;
        float4* sp = (float4*)lds_yp;
        for (int i = tid; i < n4; i += THREADS) { st[i] = gt[i]; sp[i] = gp[i]; }
        for (int i = (n4 << 2) + tid; i < navail; i += THREADS) {
            lds_yt[i] = y_true[base + i];
            lds_yp[i] = y_pred[base + i];
        }
    }
    __syncthreads();

    const int q    = tid & 3;     // lane within quad
    const int quad = tid >> 2;    // cell within block
    const int cell = cell0 + quad;

    double p_xy = 0.0, p_wh = 0.0, p_conf = 0.0, p_ce = 0.0;
    double p_nc = 0.0, p_nf = 0.0, p_ncl = 0.0;

    if (cell < n_cells) {
        // decode (b, h, w, box)
        int b    = cell / CPB_CELLS;
        int rem  = cell - b * CPB_CELLS;
        int h    = rem / (GRID_HW * NBOX);
        int rem2 = rem - h * (GRID_HW * NBOX);
        int w    = rem2 / NBOX;
        int box  = rem2 - w * NBOX;

        const float* yt = lds_yt + quad * REC;
        const float* yp = lds_yp + quad * REC;

        const float yt4 = yt[4];
        const float tx = yt[0], ty = yt[1], tw = yt[2], th = yt[3];

        // predicted box (all 4 lanes redundantly; cheap)
        const float px = 1.f / (1.f + expf(-yp[0])) + (float)w;
        const float py = 1.f / (1.f + expf(-yp[1])) + (float)h;
        const float pw = expf(yp[2]) * c_anchors[2 * box];
        const float ph = expf(yp[3]) * c_anchors[2 * box + 1];
        const float pconf = 1.f / (1.f + expf(-yp[4]));

        const float pw2 = pw * 0.5f, ph2 = ph * 0.5f;
        const float p_minx = px - pw2, p_maxx = px + pw2;
        const float p_miny = py - ph2, p_maxy = py + ph2;

        // IoU vs y_true box -> true_box_conf
        float tw2 = tw * 0.5f, th2 = th * 0.5f;
        float iw = fmaxf(fminf(p_maxx, tx + tw2) - fmaxf(p_minx, tx - tw2), 0.f);
        float ih = fmaxf(fminf(p_maxy, ty + th2) - fmaxf(p_miny, ty - th2), 0.f);
        float inter = iw * ih;
        float iou = inter / (pw * ph + tw * th - inter);
        const float true_conf = iou * yt4;

        // ---- argmax over y_true classes (4-way split, first-max semantics) ----
        float amax = -INFINITY; int aidx = 0x7fffffff;
        #pragma unroll
        for (int k = 0; k < NCLASS / 4; ++k) {
            int c = q + 4 * k;
            float v = yt[5 + c];
            if (v > amax) { amax = v; aidx = c; }
        }
        #pragma unroll
        for (int m = 1; m <= 2; m <<= 1) {
            float ov = __shfl_xor(amax, m);
            int   oi = __shfl_xor(aidx, m);
            if (ov > amax || (ov == amax && oi < aidx)) { amax = ov; aidx = oi; }
        }

        // ---- log_softmax over y_pred classes (4-way split) ----
        float lmax = -INFINITY;
        #pragma unroll
        for (int k = 0; k < NCLASS / 4; ++k)
            lmax = fmaxf(lmax, yp[5 + q + 4 * k]);
        #pragma unroll
        for (int m = 1; m <= 2; m <<= 1)
            lmax = fmaxf(lmax, __shfl_xor(lmax, m));
        float lsum = 0.f;
        #pragma unroll
        for (int k = 0; k < NCLASS / 4; ++k)
            lsum += expf(yp[5 + q + 4 * k] - lmax);
        #pragma unroll
        for (int m = 1; m <= 2; m <<= 1)
            lsum += __shfl_xor(lsum, m);
        const float ce = -(yp[5 + aidx] - lmax - logf(lsum));

        // ---- best IoU over 50 true boxes (4-way split) ----
        const float4* tb = (const float4*)(tboxes + (size_t)b * T_BOXES * 4);
        float best = -INFINITY;
        for (int t = q; t < T_BOXES; t += 4) {
            float4 bx = tb[t];
            float bw2 = bx.z * 0.5f, bh2 = bx.w * 0.5f;
            float iw2 = fmaxf(fminf(p_maxx, bx.x + bw2) - fmaxf(p_minx, bx.x - bw2), 0.f);
            float ih2 = fmaxf(fminf(p_maxy, bx.y + bh2) - fmaxf(p_miny, bx.y - bh2), 0.f);
            float ia = iw2 * ih2;
            float r  = ia / (pw * ph + bx.z * bx.w - ia);
            best = fmaxf(best, r);
        }
        #pragma unroll
        for (int m = 1; m <= 2; m <<= 1)
            best = fmaxf(best, __shfl_xor(best, m));

        // ---- per-cell contributions (lane q==0 only) ----
        if (q == 0) {
            const float cm = yt4;  // coord_mask (COORD_FACTOR=1)
            p_xy = (double)(((tx - px) * (tx - px) + (ty - py) * (ty - py)) * cm);
            p_wh = (double)(((tw - pw) * (tw - pw) + (th - ph) * (th - ph)) * cm);
            float conf_mask = ((best < 0.6f) ? 1.f : 0.f) * (1.f - yt4)  // NO_OBJECT_FACTOR=1
                            + true_conf * 5.f;                            // OBJECT_FACTOR=5
            p_conf = (double)((true_conf - pconf) * (true_conf - pconf) * conf_mask);
            p_ce   = (double)(ce * yt4);                                  // CLASS_FACTOR=1
            p_nc   = (cm > 0.f)        ? 1.0 : 0.0;
            p_nf   = (conf_mask > 0.f) ? 1.0 : 0.0;
            p_ncl  = (yt4 > 0.f)       ? 1.0 : 0.0;
        }
    }

    // ---- block reduction (wave shfl -> LDS -> one atomic per block) ----
    double v[7] = {p_xy, p_wh, p_conf, p_ce, p_nc, p_nf, p_ncl};
    #pragma unroll
    for (int k = 0; k < 7; ++k) {
        #pragma unroll
        for (int off = 32; off > 0; off >>= 1)
            v[k] += __shfl_down(v[k], off);
    }
    const int wave = tid >> 6, lane = tid & 63;
    if (lane == 0) {
        #pragma unroll
        for (int k = 0; k < 7; ++k) red[wave][k] = v[k];
    }
    __syncthreads();
    if (tid == 0) {
        #pragma unroll
        for (int k = 0; k < 7; ++k) {
            double s = red[0][k] + red[1][k] + red[2][k] + red[3][k];
            unsafeAtomicAdd(&acc[k], s);   // HW global_atomic_add_f64
        }
    }
}

__global__ void yolo_loss_final(const double* __restrict__ acc,
                                float* __restrict__ out)
{
    if (threadIdx.x == 0 && blockIdx.x == 0) {
        double nbc  = acc[4] + 1e-6;
        double nbf  = acc[5] + 1e-6;
        double nbcl = acc[6] + 1e-6;
        double loss = acc[0] / nbc * 0.5
                    + acc[1] / nbc * 0.5
                    + acc[2] / nbf * 0.5
                    + acc[3] / nbcl;
        out[0] = (float)loss;
    }
}

extern "C" void kernel_launch(void* const* d_in, const int* in_sizes, int n_in,
                              void* d_out, int out_size, void* d_ws, size_t ws_size,
                              hipStream_t stream)
{
    const float* y_true = (const float*)d_in[0];
    const float* y_pred = (const float*)d_in[1];
    const float* tboxes = (const float*)d_in[2];
    float* out  = (float*)d_out;
    double* acc = (double*)d_ws;

    const int n_cells = in_sizes[0] / REC;                 // B*13*13*5
    const int blocks  = (n_cells + CPB - 1) / CPB;         // 3380 for B=256

    hipMemsetAsync(d_ws, 0, 7 * sizeof(double), stream);
    yolo_loss_main<<<blocks, THREADS, 0, stream>>>(y_true, y_pred, tboxes, acc, n_cells);
    yolo_loss_final<<<1, 64, 0, stream>>>(acc, out);
}

// Round 2
// 195.216 us; speedup vs baseline: 2.1564x; 2.1564x over previous
//
#include <hip/hip_runtime.h>
#include <math.h>

// Problem constants (from reference)
#define GRID_HW   13
#define NBOX      5
#define NCLASS    80
#define REC       85                       // 5 + NCLASS floats per cell
#define CPB_CELLS (GRID_HW*GRID_HW*NBOX)   // 845 cells per batch element
#define T_BOXES   50
#define CPB       64                       // cells per block
#define THREADS   256

__device__ __constant__ float c_anchors[10] = {
    0.57273f, 0.677385f, 1.87446f, 2.06253f, 3.33843f,
    5.47434f, 7.88282f, 3.52778f, 9.77052f, 9.16828f};

// partial layout per block: [0]=sum_xy [1]=sum_wh [2]=sum_conf [3]=sum_ce
//                           [4]=nb_coord [5]=nb_conf [6]=nb_class  ([7]=pad)
template <int USE_ATOMIC>
__global__ __launch_bounds__(THREADS)
void yolo_loss_main(const float* __restrict__ y_true,
                    const float* __restrict__ y_pred,
                    const float* __restrict__ tboxes,
                    double* __restrict__ partials,   // USE_ATOMIC ? acc[7] : [nblocks][8]
                    int n_cells)
{
    __shared__ float lds_yt[CPB * REC];   // 21760 B
    __shared__ float lds_yp[CPB * REC];   // 21760 B
    __shared__ double red[4][7];

    const int tid   = threadIdx.x;
    const int cell0 = blockIdx.x * CPB;

    // ---- coalesced global -> LDS staging (float4) ----
    {
        const size_t base = (size_t)cell0 * REC;
        long long avail_ll = (long long)n_cells * REC - (long long)base;
        int navail = (avail_ll > (long long)(CPB * REC)) ? (CPB * REC)
                    : (avail_ll < 0 ? 0 : (int)avail_ll);
        int n4 = navail >> 2;
        const float4* gt = (const float4*)(y_true + base);
        const float4* gp = (const float4*)(y_pred + base);
        float4* st = (float4*)lds_yt;
        float4* sp = (float4*)lds_yp;
        for (int i = tid; i < n4; i += THREADS) { st[i] = gt[i]; sp[i] = gp[i]; }
        for (int i = (n4 << 2) + tid; i < navail; i += THREADS) {
            lds_yt[i] = y_true[base + i];
            lds_yp[i] = y_pred[base + i];
        }
    }
    __syncthreads();

    const int q    = tid & 3;     // lane within quad
    const int quad = tid >> 2;    // cell within block
    const int cell = cell0 + quad;

    double p_xy = 0.0, p_wh = 0.0, p_conf = 0.0, p_ce = 0.0;
    double p_nc = 0.0, p_nf = 0.0, p_ncl = 0.0;

    if (cell < n_cells) {
        // decode (b, h, w, box)
        int b    = cell / CPB_CELLS;
        int rem  = cell - b * CPB_CELLS;
        int h    = rem / (GRID_HW * NBOX);
        int rem2 = rem - h * (GRID_HW * NBOX);
        int w    = rem2 / NBOX;
        int box  = rem2 - w * NBOX;

        const float* yt = lds_yt + quad * REC;
        const float* yp = lds_yp + quad * REC;

        const float yt4 = yt[4];
        const float tx = yt[0], ty = yt[1], tw = yt[2], th = yt[3];

        // predicted box (all 4 lanes redundantly; cheap)
        const float px = 1.f / (1.f + expf(-yp[0])) + (float)w;
        const float py = 1.f / (1.f + expf(-yp[1])) + (float)h;
        const float pw = expf(yp[2]) * c_anchors[2 * box];
        const float ph = expf(yp[3]) * c_anchors[2 * box + 1];
        const float pconf = 1.f / (1.f + expf(-yp[4]));

        const float pw2 = pw * 0.5f, ph2 = ph * 0.5f;
        const float p_minx = px - pw2, p_maxx = px + pw2;
        const float p_miny = py - ph2, p_maxy = py + ph2;

        // IoU vs y_true box -> true_box_conf
        float tw2 = tw * 0.5f, th2 = th * 0.5f;
        float iw = fmaxf(fminf(p_maxx, tx + tw2) - fmaxf(p_minx, tx - tw2), 0.f);
        float ih = fmaxf(fminf(p_maxy, ty + th2) - fmaxf(p_miny, ty - th2), 0.f);
        float inter = iw * ih;
        float iou = inter / (pw * ph + tw * th - inter);
        const float true_conf = iou * yt4;

        // ---- argmax over y_true classes (4-way split, first-max semantics) ----
        float amax = -INFINITY; int aidx = 0x7fffffff;
        #pragma unroll
        for (int k = 0; k < NCLASS / 4; ++k) {
            int c = q + 4 * k;
            float v = yt[5 + c];
            if (v > amax) { amax = v; aidx = c; }
        }
        #pragma unroll
        for (int m = 1; m <= 2; m <<= 1) {
            float ov = __shfl_xor(amax, m);
            int   oi = __shfl_xor(aidx, m);
            if (ov > amax || (ov == amax && oi < aidx)) { amax = ov; aidx = oi; }
        }

        // ---- log_softmax over y_pred classes (4-way split) ----
        float lmax = -INFINITY;
        #pragma unroll
        for (int k = 0; k < NCLASS / 4; ++k)
            lmax = fmaxf(lmax, yp[5 + q + 4 * k]);
        #pragma unroll
        for (int m = 1; m <= 2; m <<= 1)
            lmax = fmaxf(lmax, __shfl_xor(lmax, m));
        float lsum = 0.f;
        #pragma unroll
        for (int k = 0; k < NCLASS / 4; ++k)
            lsum += expf(yp[5 + q + 4 * k] - lmax);
        #pragma unroll
        for (int m = 1; m <= 2; m <<= 1)
            lsum += __shfl_xor(lsum, m);
        const float ce = -(yp[5 + aidx] - lmax - logf(lsum));

        // ---- best IoU over 50 true boxes (4-way split) ----
        const float4* tb = (const float4*)(tboxes + (size_t)b * T_BOXES * 4);
        float best = -INFINITY;
        for (int t = q; t < T_BOXES; t += 4) {
            float4 bx = tb[t];
            float bw2 = bx.z * 0.5f, bh2 = bx.w * 0.5f;
            float iw2 = fmaxf(fminf(p_maxx, bx.x + bw2) - fmaxf(p_minx, bx.x - bw2), 0.f);
            float ih2 = fmaxf(fminf(p_maxy, bx.y + bh2) - fmaxf(p_miny, bx.y - bh2), 0.f);
            float ia = iw2 * ih2;
            float r  = ia / (pw * ph + bx.z * bx.w - ia);
            best = fmaxf(best, r);
        }
        #pragma unroll
        for (int m = 1; m <= 2; m <<= 1)
            best = fmaxf(best, __shfl_xor(best, m));

        // ---- per-cell contributions (lane q==0 only) ----
        if (q == 0) {
            const float cm = yt4;  // coord_mask (COORD_FACTOR=1)
            p_xy = (double)(((tx - px) * (tx - px) + (ty - py) * (ty - py)) * cm);
            p_wh = (double)(((tw - pw) * (tw - pw) + (th - ph) * (th - ph)) * cm);
            float conf_mask = ((best < 0.6f) ? 1.f : 0.f) * (1.f - yt4)  // NO_OBJECT_FACTOR=1
                            + true_conf * 5.f;                            // OBJECT_FACTOR=5
            p_conf = (double)((true_conf - pconf) * (true_conf - pconf) * conf_mask);
            p_ce   = (double)(ce * yt4);                                  // CLASS_FACTOR=1
            p_nc   = (cm > 0.f)        ? 1.0 : 0.0;
            p_nf   = (conf_mask > 0.f) ? 1.0 : 0.0;
            p_ncl  = (yt4 > 0.f)       ? 1.0 : 0.0;
        }
    }

    // ---- block reduction (wave shfl -> LDS -> ONE store (or atomic) per block) ----
    double v[7] = {p_xy, p_wh, p_conf, p_ce, p_nc, p_nf, p_ncl};
    #pragma unroll
    for (int k = 0; k < 7; ++k) {
        #pragma unroll
        for (int off = 32; off > 0; off >>= 1)
            v[k] += __shfl_down(v[k], off);
    }
    const int wave = tid >> 6, lane = tid & 63;
    if (lane == 0) {
        #pragma unroll
        for (int k = 0; k < 7; ++k) red[wave][k] = v[k];
    }
    __syncthreads();
    if (tid < 7) {
        double s = red[0][tid] + red[1][tid] + red[2][tid] + red[3][tid];
        if (USE_ATOMIC) {
            unsafeAtomicAdd(&partials[tid], s);
        } else {
            partials[(size_t)blockIdx.x * 8 + tid] = s;   // contention-free store
        }
    }
}

// Reduce nblocks partial rows -> final scalar loss.
template <int USE_ATOMIC>
__global__ __launch_bounds__(256)
void yolo_loss_final(const double* __restrict__ partials,
                     float* __restrict__ out, int nblocks)
{
    __shared__ double red[4][7];
    const int tid = threadIdx.x;
    double v[7] = {0, 0, 0, 0, 0, 0, 0};
    if (USE_ATOMIC) {
        if (tid < 7) v[0] = partials[tid];   // already summed; put in v[0] slot
        if (tid == 0) {
            // direct read path (atomic accumulation already complete)
        }
        // handled below via simple scalar path
        if (tid == 0) {
            double nbc  = partials[4] + 1e-6;
            double nbf  = partials[5] + 1e-6;
            double nbcl = partials[6] + 1e-6;
            out[0] = (float)(partials[0] / nbc * 0.5 + partials[1] / nbc * 0.5 +
                             partials[2] / nbf * 0.5 + partials[3] / nbcl);
        }
        return;
    }
    for (int i = tid; i < nblocks; i += 256) {
        const double* p = partials + (size_t)i * 8;
        #pragma unroll
        for (int k = 0; k < 7; ++k) v[k] += p[k];
    }
    #pragma unroll
    for (int k = 0; k < 7; ++k) {
        #pragma unroll
        for (int off = 32; off > 0; off >>= 1)
            v[k] += __shfl_down(v[k], off);
    }
    const int wave = tid >> 6, lane = tid & 63;
    if (lane == 0) {
        #pragma unroll
        for (int k = 0; k < 7; ++k) red[wave][k] = v[k];
    }
    __syncthreads();
    if (tid == 0) {
        double s[7];
        #pragma unroll
        for (int k = 0; k < 7; ++k)
            s[k] = red[0][k] + red[1][k] + red[2][k] + red[3][k];
        double nbc  = s[4] + 1e-6;
        double nbf  = s[5] + 1e-6;
        double nbcl = s[6] + 1e-6;
        out[0] = (float)(s[0] / nbc * 0.5 + s[1] / nbc * 0.5 +
                         s[2] / nbf * 0.5 + s[3] / nbcl);
    }
}

extern "C" void kernel_launch(void* const* d_in, const int* in_sizes, int n_in,
                              void* d_out, int out_size, void* d_ws, size_t ws_size,
                              hipStream_t stream)
{
    const float* y_true = (const float*)d_in[0];
    const float* y_pred = (const float*)d_in[1];
    const float* tboxes = (const float*)d_in[2];
    float* out  = (float*)d_out;
    double* ws  = (double*)d_ws;

    const int n_cells = in_sizes[0] / REC;                 // B*13*13*5
    const int blocks  = (n_cells + CPB - 1) / CPB;         // 3380 for B=256
    const size_t need = (size_t)blocks * 8 * sizeof(double);

    if (ws_size >= need) {
        // contention-free path: per-block partial stores + tree reduce
        yolo_loss_main<0><<<blocks, THREADS, 0, stream>>>(y_true, y_pred, tboxes, ws, n_cells);
        yolo_loss_final<0><<<1, 256, 0, stream>>>(ws, out, blocks);
    } else {
        // fallback: atomic accumulation into ws[0..6]
        hipMemsetAsync(d_ws, 0, 7 * sizeof(double), stream);
        yolo_loss_main<1><<<blocks, THREADS, 0, stream>>>(y_true, y_pred, tboxes, ws, n_cells);
        yolo_loss_final<1><<<1, 256, 0, stream>>>(ws, out, blocks);
    }
}

// Round 3
// 183.409 us; speedup vs baseline: 2.2953x; 1.0644x over previous
//
#include <hip/hip_runtime.h>
#include <math.h>

// Problem constants (from reference)
#define GRID_HW   13
#define NBOX      5
#define NCLASS    80
#define REC       85                       // 5 + NCLASS floats per cell
#define CPB_CELLS (GRID_HW*GRID_HW*NBOX)   // 845 cells per batch element
#define T_BOXES   50
#define THREADS   256
#define QPB       (THREADS/4)              // 64 cells per block

__device__ __constant__ float c_anchors[10] = {
    0.57273f, 0.677385f, 1.87446f, 2.06253f, 3.33843f,
    5.47434f, 7.88282f, 3.52778f, 9.77052f, 9.16828f};

// partial layout per block row (64 B): [0]=sum_xy [1]=sum_wh [2]=sum_conf
// [3]=sum_ce [4]=nb_coord [5]=nb_conf [6]=nb_class [7]=0 (pad for double4)
template <int USE_ATOMIC>
__global__ __launch_bounds__(THREADS, 6)
void yolo_loss_main(const float* __restrict__ y_true,
                    const float* __restrict__ y_pred,
                    const float* __restrict__ tboxes,
                    double* __restrict__ partials,
                    int n_cells)
{
    __shared__ double red[4][8];

    const int tid  = threadIdx.x;
    const int q    = tid & 3;     // lane within quad
    const int quad = tid >> 2;    // cell within block
    const int cell = blockIdx.x * QPB + quad;

    double p_xy = 0.0, p_wh = 0.0, p_conf = 0.0, p_ce = 0.0;
    double p_nc = 0.0, p_nf = 0.0, p_ncl = 0.0;

    if (cell < n_cells) {
        // decode (b, h, w, box)
        int b    = cell / CPB_CELLS;
        int rem  = cell - b * CPB_CELLS;
        int h    = rem / (GRID_HW * NBOX);
        int rem2 = rem - h * (GRID_HW * NBOX);
        int w    = rem2 / NBOX;
        int box  = rem2 - w * NBOX;

        const float* __restrict__ yt = y_true + (size_t)cell * REC;
        const float* __restrict__ yp = y_pred + (size_t)cell * REC;

        // head loads (broadcast within quad -> single L1 access each)
        const float tx = yt[0], ty = yt[1], tw = yt[2], th = yt[3], yt4 = yt[4];
        const float r0 = yp[0], r1 = yp[1], r2 = yp[2], r3 = yp[3], r4 = yp[4];

        // predicted box (redundant across the 4 quad lanes; cheap)
        const float px = 1.f / (1.f + expf(-r0)) + (float)w;
        const float py = 1.f / (1.f + expf(-r1)) + (float)h;
        const float pw = expf(r2) * c_anchors[2 * box];
        const float ph = expf(r3) * c_anchors[2 * box + 1];
        const float pconf = 1.f / (1.f + expf(-r4));

        const float pw2 = pw * 0.5f, ph2 = ph * 0.5f;
        const float p_minx = px - pw2, p_maxx = px + pw2;
        const float p_miny = py - ph2, p_maxy = py + ph2;

        // IoU vs y_true box -> true_box_conf
        float tw2 = tw * 0.5f, th2 = th * 0.5f;
        float iw = fmaxf(fminf(p_maxx, tx + tw2) - fmaxf(p_minx, tx - tw2), 0.f);
        float ih = fmaxf(fminf(p_maxy, ty + th2) - fmaxf(p_miny, ty - th2), 0.f);
        float inter = iw * ih;
        float iou = inter / (pw * ph + tw * th - inter);
        const float true_conf = iou * yt4;

        // ---- pass 1: y_true argmax + y_pred max (4-way split, direct loads) ----
        float amax = -INFINITY; int aidx = 0x7fffffff;
        float lmax = -INFINITY;
        #pragma unroll
        for (int k = 0; k < NCLASS / 4; ++k) {
            int c = q + 4 * k;
            float tv = yt[5 + c];
            float pv = yp[5 + c];
            if (tv > amax) { amax = tv; aidx = c; }
            lmax = fmaxf(lmax, pv);
        }
        #pragma unroll
        for (int m = 1; m <= 2; m <<= 1) {
            float ov = __shfl_xor(amax, m);
            int   oi = __shfl_xor(aidx, m);
            if (ov > amax || (ov == amax && oi < aidx)) { amax = ov; aidx = oi; }
            lmax = fmaxf(lmax, __shfl_xor(lmax, m));
        }

        // ---- pass 2: sum exp (reloads are L1-hot) ----
        float lsum = 0.f;
        #pragma unroll
        for (int k = 0; k < NCLASS / 4; ++k)
            lsum += expf(yp[5 + q + 4 * k] - lmax);
        #pragma unroll
        for (int m = 1; m <= 2; m <<= 1)
            lsum += __shfl_xor(lsum, m);
        const float ce = -(yp[5 + aidx] - lmax - logf(lsum));

        // ---- best IoU over 50 true boxes (4-way split; broadcast across quads) ----
        const float4* tb = (const float4*)(tboxes + (size_t)b * T_BOXES * 4);
        float best = -INFINITY;
        #pragma unroll 2
        for (int t = q; t < T_BOXES; t += 4) {
            float4 bx = tb[t];
            float bw2 = bx.z * 0.5f, bh2 = bx.w * 0.5f;
            float iw2 = fmaxf(fminf(p_maxx, bx.x + bw2) - fmaxf(p_minx, bx.x - bw2), 0.f);
            float ih2 = fmaxf(fminf(p_maxy, bx.y + bh2) - fmaxf(p_miny, bx.y - bh2), 0.f);
            float ia = iw2 * ih2;
            float r  = ia / (pw * ph + bx.z * bx.w - ia);
            best = fmaxf(best, r);
        }
        #pragma unroll
        for (int m = 1; m <= 2; m <<= 1)
            best = fmaxf(best, __shfl_xor(best, m));

        // ---- per-cell contributions (lane q==0 only) ----
        if (q == 0) {
            const float cm = yt4;  // coord_mask (COORD_FACTOR=1)
            p_xy = (double)(((tx - px) * (tx - px) + (ty - py) * (ty - py)) * cm);
            p_wh = (double)(((tw - pw) * (tw - pw) + (th - ph) * (th - ph)) * cm);
            float conf_mask = ((best < 0.6f) ? 1.f : 0.f) * (1.f - yt4)  // NO_OBJECT_FACTOR=1
                            + true_conf * 5.f;                            // OBJECT_FACTOR=5
            p_conf = (double)((true_conf - pconf) * (true_conf - pconf) * conf_mask);
            p_ce   = (double)(ce * yt4);                                  // CLASS_FACTOR=1
            p_nc   = (cm > 0.f)        ? 1.0 : 0.0;
            p_nf   = (conf_mask > 0.f) ? 1.0 : 0.0;
            p_ncl  = (yt4 > 0.f)       ? 1.0 : 0.0;
        }
    }

    // ---- block reduction (wave shfl -> LDS -> one 64B store per block) ----
    double v[7] = {p_xy, p_wh, p_conf, p_ce, p_nc, p_nf, p_ncl};
    #pragma unroll
    for (int k = 0; k < 7; ++k) {
        #pragma unroll
        for (int off = 32; off > 0; off >>= 1)
            v[k] += __shfl_down(v[k], off);
    }
    const int wave = tid >> 6, lane = tid & 63;
    if (lane == 0) {
        #pragma unroll
        for (int k = 0; k < 7; ++k) red[wave][k] = v[k];
    }
    __syncthreads();
    if (tid < 8) {
        double s = (tid < 7) ? (red[0][tid] + red[1][tid] + red[2][tid] + red[3][tid])
                             : 0.0;
        if (USE_ATOMIC) {
            if (tid < 7) unsafeAtomicAdd(&partials[tid], s);
        } else {
            partials[(size_t)blockIdx.x * 8 + tid] = s;   // contention-free store
        }
    }
}

// Reduce nblocks partial rows -> final scalar loss.
template <int USE_ATOMIC>
__global__ __launch_bounds__(1024)
void yolo_loss_final(const double* __restrict__ partials,
                     float* __restrict__ out, int nblocks)
{
    __shared__ double red[16][8];
    const int tid = threadIdx.x;

    if (USE_ATOMIC) {
        if (tid == 0) {
            double nbc  = partials[4] + 1e-6;
            double nbf  = partials[5] + 1e-6;
            double nbcl = partials[6] + 1e-6;
            out[0] = (float)(partials[0] / nbc * 0.5 + partials[1] / nbc * 0.5 +
                             partials[2] / nbf * 0.5 + partials[3] / nbcl);
        }
        return;
    }

    double v[7] = {0, 0, 0, 0, 0, 0, 0};
    for (int i = tid; i < nblocks; i += 1024) {
        const double4* p = (const double4*)(partials + (size_t)i * 8);  // 32B-aligned
        double4 a = p[0];
        double4 b = p[1];
        v[0] += a.x; v[1] += a.y; v[2] += a.z; v[3] += a.w;
        v[4] += b.x; v[5] += b.y; v[6] += b.z;   // b.w is the zero pad
    }
    #pragma unroll
    for (int k = 0; k < 7; ++k) {
        #pragma unroll
        for (int off = 32; off > 0; off >>= 1)
            v[k] += __shfl_down(v[k], off);
    }
    const int wave = tid >> 6, lane = tid & 63;
    if (lane == 0) {
        #pragma unroll
        for (int k = 0; k < 7; ++k) red[wave][k] = v[k];
    }
    __syncthreads();
    if (tid == 0) {
        double s[7];
        #pragma unroll
        for (int k = 0; k < 7; ++k) {
            double acc = 0.0;
            #pragma unroll
            for (int wv = 0; wv < 16; ++wv) acc += red[wv][k];
            s[k] = acc;
        }
        double nbc  = s[4] + 1e-6;
        double nbf  = s[5] + 1e-6;
        double nbcl = s[6] + 1e-6;
        out[0] = (float)(s[0] / nbc * 0.5 + s[1] / nbc * 0.5 +
                         s[2] / nbf * 0.5 + s[3] / nbcl);
    }
}

extern "C" void kernel_launch(void* const* d_in, const int* in_sizes, int n_in,
                              void* d_out, int out_size, void* d_ws, size_t ws_size,
                              hipStream_t stream)
{
    const float* y_true = (const float*)d_in[0];
    const float* y_pred = (const float*)d_in[1];
    const float* tboxes = (const float*)d_in[2];
    float* out  = (float*)d_out;
    double* ws  = (double*)d_ws;

    const int n_cells = in_sizes[0] / REC;                 // B*13*13*5 = 216320
    const int blocks  = (n_cells + QPB - 1) / QPB;         // 3380 for B=256
    const size_t need = (size_t)blocks * 8 * sizeof(double);

    if (ws_size >= need) {
        // contention-free path: per-block partial stores + tree reduce
        yolo_loss_main<0><<<blocks, THREADS, 0, stream>>>(y_true, y_pred, tboxes, ws, n_cells);
        yolo_loss_final<0><<<1, 1024, 0, stream>>>(ws, out, blocks);
    } else {
        // fallback: atomic accumulation into ws[0..6]
        hipMemsetAsync(d_ws, 0, 7 * sizeof(double), stream);
        yolo_loss_main<1><<<blocks, THREADS, 0, stream>>>(y_true, y_pred, tboxes, ws, n_cells);
        yolo_loss_final<1><<<1, 64, 0, stream>>>(ws, out, blocks);
    }
}